// Round 5
// baseline (41.846 us; speedup 1.0000x reference)
//
#include <hip/hip_runtime.h>

// Problem constants (from reference): B=4, N=512, K=20, C=32
#define Bb 4
#define Nn 512
#define Kk 20
#define Cc 32
#define BN_PER_BLOCK 4

typedef float f32x4 __attribute__((ext_vector_type(4)));

// out[b, n, k, c1, c2] = trans[c1,c2] + length[k,c2] + slide[b,n,k,c2]
//                        + (k == (N-1)-n ? E[b,N-1,c1] : 0)
//                        + (n == 0 ? init[c2] : 0)
// slide[b,n,k,c2] = sum_{j=n}^{min(n+k,N)-1} E[b,j,c2]   (k frames, clipped)
//
// Each block processes BN_PER_BLOCK consecutive bn=(b,n) pairs -> writes a
// 320 KB contiguous output region sequentially in time. Grid = 511 blocks
// (2 blocks/CU): fewer concurrent write streams for better HBM page
// locality (fill kernel saturates 6.7 TB/s at ~10% occupancy with long
// sequential streams; full-occupancy 1KB-interleaved writes measured 5.1).
// Thread layout per bn: c1 = tid/8, q = tid%8 (float4 chunk along c2).
__global__ __launch_bounds__(256) void semimarkov_scores_kernel(
    const float* __restrict__ trans,   // (C,C)
    const float* __restrict__ emis,    // (B,N,C)
    const float* __restrict__ initv,   // (C,)
    const float* __restrict__ lens,    // (K,C)
    float* __restrict__ out)           // (B, N-1, K, C, C)
{
    const int tid = threadIdx.x;
    const int c1  = tid >> 3;          // 0..31
    const int q   = tid & 7;           // float4 index along c2 (c2 = 4q..4q+3)

    // Block-invariant: transition row chunk
    const f32x4 t4 = *reinterpret_cast<const f32x4*>(&trans[c1 * Cc + q * 4]);

    #pragma unroll
    for (int j = 0; j < BN_PER_BLOCK; ++j) {
        const int bn = blockIdx.x * BN_PER_BLOCK + j;
        if (bn >= Bb * (Nn - 1)) break;
        const int b = bn / (Nn - 1);
        const int n = bn - b * (Nn - 1);

        f32x4 add4 = t4;
        if (n == 0) {
            add4 += *reinterpret_cast<const f32x4*>(&initv[q * 4]);
        }

        // eos: added at k_eos = (N-1)-n (always >=1 here), only if k_eos < K.
        const int   k_eos  = (Nn - 1) - n;
        const float e_last = (k_eos < Kk)
            ? emis[((size_t)b * Nn + (Nn - 1)) * Cc + c1]
            : 0.0f;

        f32x4 s4 = (f32x4)(0.0f);      // running window sum (c2 chunk)
        const float* eb = &emis[((size_t)b * Nn + n) * Cc + q * 4];
        float* ob = &out[(size_t)bn * (size_t)(Kk * Cc * Cc)
                         + (size_t)(c1 * Cc + q * 4)];

        #pragma unroll
        for (int k = 0; k < Kk; ++k) {
            const f32x4 l4 = *reinterpret_cast<const f32x4*>(&lens[k * Cc + q * 4]);
            f32x4 v = add4 + l4 + s4;
            if (k == k_eos) {
                v += (f32x4)(e_last);
            }
            *reinterpret_cast<f32x4*>(&ob[(size_t)k * (Cc * Cc)]) = v;

            // extend window by frame n+k (exists iff n+k <= N-1)
            if (n + k < Nn) {
                s4 += *reinterpret_cast<const f32x4*>(&eb[(size_t)k * Cc]);
            }
        }
    }
}

extern "C" void kernel_launch(void* const* d_in, const int* in_sizes, int n_in,
                              void* d_out, int out_size, void* d_ws, size_t ws_size,
                              hipStream_t stream) {
    const float* trans = (const float*)d_in[0];   // (C,C)
    const float* emis  = (const float*)d_in[1];   // (B,N,C)
    const float* initv = (const float*)d_in[2];   // (C,)
    const float* lens  = (const float*)d_in[3];   // (K,C)
    float* out = (float*)d_out;                   // (B, N-1, K, C, C)

    const int total = Bb * (Nn - 1);              // 2044 bn pairs
    const int grid  = (total + BN_PER_BLOCK - 1) / BN_PER_BLOCK;  // 511 blocks
    semimarkov_scores_kernel<<<grid, 256, 0, stream>>>(trans, emis, initv, lens, out);
}

// Round 6
// 30.914 us; speedup vs baseline: 1.3536x; 1.3536x over previous
//
#include <hip/hip_runtime.h>

// Problem constants (from reference): B=4, N=512, K=20, C=32
#define Bb 4
#define Nn 512
#define Kk 20
#define Cc 32

typedef float f32x4 __attribute__((ext_vector_type(4)));

// out[b, n, k, c1, c2] = trans[c1,c2] + length[k,c2] + slide[b,n,k,c2]
//                        + (k == (N-1)-n ? E[b,N-1,c1] : 0)
//                        + (n == 0 ? init[c2] : 0)
// slide[b,n,k,c2] = sum_{j=n}^{min(n+k,N)-1} E[b,j,c2]   (k frames, clipped)
//
// One block per (b,n). Stage base[k][c2] = lens + slide (+init) in LDS using
// wave-0 lanes 0..31 (all 40 global loads issued independently, prefix sum in
// registers), then every thread's store stream is 20 ds_read_b128 + 20
// global stores with NO global-load dependency chain. R5 showed achieved
// write BW scales with how well load latency is hidden; this removes the
// loads from the hot path entirely. NT stores hurt (R3); low concurrency
// hurt (R5); keep 2044 blocks x 256 threads = full 32 waves/CU residency.
__global__ __launch_bounds__(256) void semimarkov_scores_kernel(
    const float* __restrict__ trans,   // (C,C)
    const float* __restrict__ emis,    // (B,N,C)
    const float* __restrict__ initv,   // (C,)
    const float* __restrict__ lens,    // (K,C)
    float* __restrict__ out)           // (B, N-1, K, C, C)
{
    __shared__ float base[Kk][Cc];     // 2560 B

    const int tid = threadIdx.x;
    const int c1  = tid >> 3;          // 0..31
    const int q   = tid & 7;           // float4 index along c2 (c2 = 4q..4q+3)
    const int bn  = blockIdx.x;        // b*(N-1) + n
    const int b   = bn / (Nn - 1);
    const int n   = bn - b * (Nn - 1);

    // Per-thread invariants (issue before the barrier so latency overlaps)
    const f32x4 t4 = *reinterpret_cast<const f32x4*>(&trans[c1 * Cc + q * 4]);
    const int   k_eos  = (Nn - 1) - n;                 // >= 1 always
    const float e_last = (k_eos < Kk)
        ? emis[((size_t)b * Nn + (Nn - 1)) * Cc + c1]
        : 0.0f;

    // Stage base[k][c2] with 32 lanes of wave 0.
    if (tid < Cc) {
        const int c2 = tid;
        float l[Kk], e[Kk];
        const float* ebs = &emis[((size_t)b * Nn + n) * Cc + c2];
        #pragma unroll
        for (int k = 0; k < Kk; ++k) {
            l[k] = lens[k * Cc + c2];                  // independent loads
            e[k] = (n + k < Nn) ? ebs[(size_t)k * Cc] : 0.0f;
        }
        float s = (n == 0) ? initv[c2] : 0.0f;
        #pragma unroll
        for (int k = 0; k < Kk; ++k) {
            base[k][c2] = l[k] + s;                    // slide[k] excludes frame n+k
            s += e[k];
        }
    }
    __syncthreads();

    float* ob = &out[(size_t)bn * (size_t)(Kk * Cc * Cc)
                     + (size_t)(c1 * Cc + q * 4)];
    #pragma unroll
    for (int k = 0; k < Kk; ++k) {
        f32x4 v = t4 + *reinterpret_cast<const f32x4*>(&base[k][q * 4]);
        if (k == k_eos) {
            v += (f32x4)(e_last);
        }
        *reinterpret_cast<f32x4*>(&ob[(size_t)k * (Cc * Cc)]) = v;
    }
}

extern "C" void kernel_launch(void* const* d_in, const int* in_sizes, int n_in,
                              void* d_out, int out_size, void* d_ws, size_t ws_size,
                              hipStream_t stream) {
    const float* trans = (const float*)d_in[0];   // (C,C)
    const float* emis  = (const float*)d_in[1];   // (B,N,C)
    const float* initv = (const float*)d_in[2];   // (C,)
    const float* lens  = (const float*)d_in[3];   // (K,C)
    float* out = (float*)d_out;                   // (B, N-1, K, C, C)

    const int grid = Bb * (Nn - 1);               // 2044 blocks
    semimarkov_scores_kernel<<<grid, 256, 0, stream>>>(trans, emis, initv, lens, out);
}